// Round 3
// baseline (987.602 us; speedup 1.0000x reference)
//
#include <hip/hip_runtime.h>
#include <hip/hip_bf16.h>

#define NA 8192
#define NB 8192
#define NE 32768
#define NC 8
#define CHW 2048   // 8*16*16

// ---------------- CSR build (tiny kernels, ~20us total) ----------------

__global__ __launch_bounds__(256) void zero_two_kernel(int* a, int* b, int n) {
    int i = blockIdx.x * 256 + threadIdx.x;
    if (i < n) { a[i] = 0; b[i] = 0; }
}

__global__ __launch_bounds__(256) void hist_kernel(
    const int* __restrict__ dst, int* __restrict__ cnt, int n) {
    int i = blockIdx.x * 256 + threadIdx.x;
    if (i < n) atomicAdd(&cnt[dst[i]], 1);
}

// single-block exclusive scan over n=8192 counts -> row[0..n], cursor copy
__global__ __launch_bounds__(256) void scan_kernel(
    const int* __restrict__ cnt, int* __restrict__ row, int* __restrict__ cur, int n) {
    __shared__ int part[256];
    const int t = threadIdx.x;
    const int chunk = (n + 255) / 256;      // 32 for n=8192
    const int base = t * chunk;
    int sum = 0;
    for (int j = 0; j < chunk; ++j) { int idx = base + j; if (idx < n) sum += cnt[idx]; }
    part[t] = sum;
    __syncthreads();
    if (t == 0) {
        int run = 0;
        for (int i = 0; i < 256; ++i) { int tmp = part[i]; part[i] = run; run += tmp; }
    }
    __syncthreads();
    int run = part[t];
    for (int j = 0; j < chunk; ++j) {
        int idx = base + j;
        if (idx < n) { row[idx] = run; cur[idx] = run; run += cnt[idx]; }
    }
    if (t == 255) row[n] = run;             // chunk*256 == n exactly (8192)
}

__global__ __launch_bounds__(256) void scatter_kernel(
    const int* __restrict__ dst, int* __restrict__ cur, int* __restrict__ perm, int n) {
    int i = blockIdx.x * 256 + threadIdx.x;
    if (i < n) { int p = atomicAdd(&cur[dst[i]], 1); perm[p] = i; }
}

// ---------------- fused per-dst-node kernel ----------------
// One block (256 threads) per destination node n:
//   v = feat_dst[n] (LDS, once)
//   for each incident edge e (CSR):  u = feat_src[src[e]] (prefetched)
//     ef = u + v (LDS, zero halo) ; Wh = conv3x3(ef) + b -> nontemporal store
//     macc += u + Wh   (registers)
//   h[n] = macc / deg  (single coalesced write; deg==0 -> 0)
__global__ __launch_bounds__(256) void node_kernel(
    const float* __restrict__ feat_src,   // [Nsrc, 2048]
    const float* __restrict__ feat_dst,   // [Ndst, 2048]
    const float* __restrict__ Wc,         // [8,8,3,3]
    const float* __restrict__ bias,       // [8]
    const int*   __restrict__ src_idx,    // [E]
    const int*   __restrict__ row,        // [Ndst+1]
    const int*   __restrict__ perm,       // [E] edge ids grouped by dst
    float*       __restrict__ Wh_out,     // [E, 2048]
    float*       __restrict__ h_out)      // [Ndst, 2048]
{
    __shared__ float s_ef[NC][18][18];    // zero halo -> branch-free conv
    __shared__ float s_u[CHW];
    __shared__ float s_v[CHW];
    __shared__ float s_w[NC * NC * 9];
    __shared__ float s_b[NC];

    const int n   = blockIdx.x;
    const int tid = threadIdx.x;
    const int beg = row[n];
    const int end = row[n + 1];

    // zero halo region + stage weights/bias + v
    float* efp = &s_ef[0][0][0];
    for (int i = tid; i < NC * 18 * 18; i += 256) efp[i] = 0.0f;
    for (int i = tid; i < NC * NC * 9; i += 256) s_w[i] = Wc[i];
    if (tid < NC) s_b[tid] = bias[tid];
    {
        const float4* vp = (const float4*)(feat_dst + (size_t)n * CHW);
        ((float4*)s_v)[tid]       = vp[tid];
        ((float4*)s_v)[tid + 256] = vp[tid + 256];
    }

    const int y = tid >> 4;
    const int x = tid & 15;
    float macc[NC];
    #pragma unroll
    for (int co = 0; co < NC; ++co) macc[co] = 0.0f;

    // prefetch first edge's u
    float4 ua = make_float4(0.f, 0.f, 0.f, 0.f), ub = ua;
    if (beg < end) {
        const float4* up = (const float4*)(feat_src + (size_t)src_idx[perm[beg]] * CHW);
        ua = up[tid]; ub = up[tid + 256];
    }
    __syncthreads();

    for (int i = beg; i < end; ++i) {
        const int e = perm[i];

        // stage ef = u + v (interior) and keep u
        #pragma unroll
        for (int k = 0; k < 2; ++k) {
            int i4 = tid + k * 256;
            float4 u = k ? ub : ua;
            float4 v = ((const float4*)s_v)[i4];
            ((float4*)s_u)[i4] = u;
            int bse = i4 * 4;
            int c  = bse >> 8;
            int yy = (bse >> 4) & 15;
            int xx = bse & 15;                 // 0,4,8,12
            s_ef[c][yy + 1][xx + 1] = u.x + v.x;
            s_ef[c][yy + 1][xx + 2] = u.y + v.y;
            s_ef[c][yy + 1][xx + 3] = u.z + v.z;
            s_ef[c][yy + 1][xx + 4] = u.w + v.w;
        }
        __syncthreads();

        // prefetch next edge's u (latency hides under the conv)
        if (i + 1 < end) {
            const float4* up = (const float4*)(feat_src + (size_t)src_idx[perm[i + 1]] * CHW);
            ua = up[tid]; ub = up[tid + 256];
        }

        // conv3x3: register-tiled over output channels (low VGPR)
        float wh[NC];
        #pragma unroll
        for (int co = 0; co < NC; ++co) wh[co] = s_b[co];
        #pragma unroll
        for (int ci = 0; ci < NC; ++ci) {
            float p[9];
            #pragma unroll
            for (int ky = 0; ky < 3; ++ky)
                #pragma unroll
                for (int kx = 0; kx < 3; ++kx)
                    p[ky * 3 + kx] = s_ef[ci][y + ky][x + kx];
            #pragma unroll
            for (int co = 0; co < NC; ++co)
                #pragma unroll
                for (int t = 0; t < 9; ++t)
                    wh[co] = fmaf(p[t], s_w[(co * NC + ci) * 9 + t], wh[co]);
        }

        float* whp = Wh_out + (size_t)e * CHW;
        #pragma unroll
        for (int co = 0; co < NC; ++co) {
            const int o = co * 256 + tid;
            __builtin_nontemporal_store(wh[co], &whp[o]);  // Wh streamed, keep L3 for feats
            macc[co] += s_u[o] + wh[co];
        }
        __syncthreads();   // before next edge overwrites s_ef / s_u
    }

    // h = mean (deg==0 -> macc==0 -> writes 0, matching DGL semantics)
    const int deg = end - beg;
    const float inv = deg > 0 ? 1.0f / (float)deg : 0.0f;
    float* hp = h_out + (size_t)n * CHW;
    #pragma unroll
    for (int co = 0; co < NC; ++co)
        hp[co * 256 + tid] = macc[co] * inv;
}

extern "C" void kernel_launch(void* const* d_in, const int* in_sizes, int n_in,
                              void* d_out, int out_size, void* d_ws, size_t ws_size,
                              hipStream_t stream) {
    const float* feat_a = (const float*)d_in[0];
    const float* feat_b = (const float*)d_in[1];
    const float* W_e1   = (const float*)d_in[2];
    const float* b_e1   = (const float*)d_in[3];
    const float* W_e2   = (const float*)d_in[4];
    const float* b_e2   = (const float*)d_in[5];
    const int*   src_e1 = (const int*)d_in[6];
    const int*   dst_e1 = (const int*)d_in[7];
    const int*   src_e2 = (const int*)d_in[8];
    const int*   dst_e2 = (const int*)d_in[9];

    float* out = (float*)d_out;
    float* h_a = out;                                  // [NA, 2048]
    float* h_b = out + (size_t)NA * CHW;               // [NB, 2048]
    float* Wh1 = out + (size_t)(NA + NB) * CHW;        // [E, 2048]
    float* Wh2 = Wh1 + (size_t)NE * CHW;               // [E, 2048]

    // workspace layout (ints; ws_size ~2GB per harness poison size, we use ~460KB)
    int* ws    = (int*)d_ws;
    int* cnt1  = ws;                  // [NB]   etype1 dst counts
    int* row1  = cnt1 + NB;           // [NB+1]
    int* cur1  = row1 + NB + 1;       // [NB]
    int* perm1 = cur1 + NB;           // [NE]
    int* cnt2  = perm1 + NE;          // [NA]
    int* row2  = cnt2 + NA;           // [NA+1]
    int* cur2  = row2 + NA + 1;       // [NA]
    int* perm2 = cur2 + NA;           // [NE]

    // CSR build (stream-ordered)
    zero_two_kernel<<<(NB + 255) / 256, 256, 0, stream>>>(cnt1, cnt2, NB);
    hist_kernel<<<(NE + 255) / 256, 256, 0, stream>>>(dst_e1, cnt1, NE);
    hist_kernel<<<(NE + 255) / 256, 256, 0, stream>>>(dst_e2, cnt2, NE);
    scan_kernel<<<1, 256, 0, stream>>>(cnt1, row1, cur1, NB);
    scan_kernel<<<1, 256, 0, stream>>>(cnt2, row2, cur2, NA);
    scatter_kernel<<<(NE + 255) / 256, 256, 0, stream>>>(dst_e1, cur1, perm1, NE);
    scatter_kernel<<<(NE + 255) / 256, 256, 0, stream>>>(dst_e2, cur2, perm2, NE);

    // etype e1: a -> b   (writes Wh1 and h_b)
    node_kernel<<<NB, 256, 0, stream>>>(feat_a, feat_b, W_e1, b_e1,
                                        src_e1, row1, perm1, Wh1, h_b);
    // etype e2: b -> a   (writes Wh2 and h_a)
    node_kernel<<<NA, 256, 0, stream>>>(feat_b, feat_a, W_e2, b_e2,
                                        src_e2, row2, perm2, Wh2, h_a);
}

// Round 4
// 641.579 us; speedup vs baseline: 1.5393x; 1.5393x over previous
//
#include <hip/hip_runtime.h>
#include <hip/hip_bf16.h>

#define NA 8192
#define NB 8192
#define NE 32768
#define NC 8
#define CHW 2048   // 8*16*16
#define EPB 4      // edges per block

// zero h region (float4) + cnt region (int4)
__global__ __launch_bounds__(256) void zero_kernel(
    float4* __restrict__ h, size_t nh4, int4* __restrict__ cnt, size_t nc4)
{
    const float4 z4 = make_float4(0.f, 0.f, 0.f, 0.f);
    const int4 zi4 = make_int4(0, 0, 0, 0);
    size_t stride = (size_t)gridDim.x * blockDim.x;
    for (size_t i = (size_t)blockIdx.x * blockDim.x + threadIdx.x; i < nh4; i += stride)
        h[i] = z4;
    for (size_t i = (size_t)blockIdx.x * blockDim.x + threadIdx.x; i < nc4; i += stride)
        cnt[i] = zi4;
}

__global__ __launch_bounds__(256) void hist_kernel(
    const int* __restrict__ dst, int* __restrict__ cnt, int n) {
    int i = blockIdx.x * 256 + threadIdx.x;
    if (i < n) atomicAdd(&cnt[dst[i]], 1);
}

// 4 edges per block, 256 threads. Per thread: one spatial position across the
// 4 edges, all 8 output channels. Weights are loaded LDS->VGPR once per ci and
// reused across the 4 edges (amortizes the dominant DS-read stream).
// h aggregation: atomicAdd((u + Wh) / indeg[dst]) -> no finalize pass.
__global__ __launch_bounds__(256, 3) void edge4_kernel(
    const float* __restrict__ feat_src,   // [Nsrc, 2048]
    const float* __restrict__ feat_dst,   // [Ndst, 2048]
    const float* __restrict__ Wc,         // [8,8,3,3] OIHW
    const float* __restrict__ bias,       // [8]
    const int*   __restrict__ src_idx,    // [E]
    const int*   __restrict__ dst_idx,    // [E]
    const int*   __restrict__ cnt,        // [Ndst] in-degree (>=1 for any observed dst)
    float*       __restrict__ Wh_out,     // [E, 2048]
    float*       __restrict__ h_acc)      // [Ndst, 2048] pre-zeroed
{
    __shared__ float s_ef[EPB][NC][18][18];  // zero halo -> branch-free conv
    __shared__ float s_w[NC][NC][12];        // [ci][co][t] padded to 12 for aligned b128
    __shared__ float s_b[NC];

    const int tid = threadIdx.x;
    const int e0  = blockIdx.x * EPB;

    int srcs[EPB], dsts[EPB];
    #pragma unroll
    for (int g = 0; g < EPB; ++g) { srcs[g] = src_idx[e0 + g]; dsts[g] = dst_idx[e0 + g]; }

    // zero only the halo ring: 68 elems per 18x18 plane
    for (int i = tid; i < EPB * NC * 68; i += 256) {
        int hp = i % 68;
        int pl = i / 68;
        int eg = pl >> 3, c = pl & 7;
        int yy, xx;
        if (hp < 18)      { yy = 0;       xx = hp; }
        else if (hp < 36) { yy = 17;      xx = hp - 18; }
        else if (hp < 52) { yy = hp - 35; xx = 0; }      // rows 1..16
        else              { yy = hp - 51; xx = 17; }
        s_ef[eg][c][yy][xx] = 0.0f;
    }
    // repack weights [co][ci][t] -> [ci][co][t(12)]
    for (int i = tid; i < NC * NC * 9; i += 256) {
        int co = i / 72, r = i % 72, ci = r / 9, t = r % 9;
        s_w[ci][co][t] = Wc[i];
    }
    if (tid < NC) s_b[tid] = bias[tid];

    // stage ef = u + v for 4 edges (float4-vectorized gathers)
    #pragma unroll
    for (int g = 0; g < EPB; ++g) {
        const float4* up = (const float4*)(feat_src + (size_t)srcs[g] * CHW);
        const float4* vp = (const float4*)(feat_dst + (size_t)dsts[g] * CHW);
        #pragma unroll
        for (int k = 0; k < 2; ++k) {
            int i4 = tid + k * 256;
            float4 u = up[i4];
            float4 v = vp[i4];
            int base = i4 * 4;
            int c  = base >> 8;
            int yy = (base >> 4) & 15;
            int xx = base & 15;              // 0,4,8,12
            s_ef[g][c][yy + 1][xx + 1] = u.x + v.x;
            s_ef[g][c][yy + 1][xx + 2] = u.y + v.y;
            s_ef[g][c][yy + 1][xx + 3] = u.z + v.z;
            s_ef[g][c][yy + 1][xx + 4] = u.w + v.w;
        }
    }
    __syncthreads();

    const int y = tid >> 4;
    const int x = tid & 15;

    float wh[EPB][NC];
    #pragma unroll
    for (int g = 0; g < EPB; ++g)
        #pragma unroll
        for (int co = 0; co < NC; ++co) wh[g][co] = s_b[co];

    #pragma unroll
    for (int ci = 0; ci < NC; ++ci) {
        // weights for this input channel -> VGPRs, shared across 4 edges
        float w[NC][9];
        #pragma unroll
        for (int co = 0; co < NC; ++co)
            #pragma unroll
            for (int t = 0; t < 9; ++t) w[co][t] = s_w[ci][co][t];
        #pragma unroll
        for (int g = 0; g < EPB; ++g) {
            float p[9];
            #pragma unroll
            for (int ky = 0; ky < 3; ++ky)
                #pragma unroll
                for (int kx = 0; kx < 3; ++kx)
                    p[ky * 3 + kx] = s_ef[g][ci][y + ky][x + kx];
            #pragma unroll
            for (int co = 0; co < NC; ++co)
                #pragma unroll
                for (int t = 0; t < 9; ++t)
                    wh[g][co] = fmaf(p[t], w[co][t], wh[g][co]);
        }
    }

    // epilogue: stream Wh, atomically accumulate (u + Wh)/deg into h[dst]
    #pragma unroll
    for (int g = 0; g < EPB; ++g) {
        const int e = e0 + g, d = dsts[g], s = srcs[g];
        const float inv = 1.0f / (float)cnt[d];
        float*       whp = Wh_out + (size_t)e * CHW;
        const float* up  = feat_src + (size_t)s * CHW;
        float*       hp  = h_acc + (size_t)d * CHW;
        #pragma unroll
        for (int co = 0; co < NC; ++co) {
            const int o = co * 256 + tid;
            const float whv = wh[g][co];
            __builtin_nontemporal_store(whv, &whp[o]);   // Wh streamed, keep L3 for feats
            atomicAdd(&hp[o], (up[o] + whv) * inv);
        }
    }
}

extern "C" void kernel_launch(void* const* d_in, const int* in_sizes, int n_in,
                              void* d_out, int out_size, void* d_ws, size_t ws_size,
                              hipStream_t stream) {
    const float* feat_a = (const float*)d_in[0];
    const float* feat_b = (const float*)d_in[1];
    const float* W_e1   = (const float*)d_in[2];
    const float* b_e1   = (const float*)d_in[3];
    const float* W_e2   = (const float*)d_in[4];
    const float* b_e2   = (const float*)d_in[5];
    const int*   src_e1 = (const int*)d_in[6];
    const int*   dst_e1 = (const int*)d_in[7];
    const int*   src_e2 = (const int*)d_in[8];
    const int*   dst_e2 = (const int*)d_in[9];

    float* out = (float*)d_out;
    float* h_a = out;                                  // [NA, 2048]
    float* h_b = out + (size_t)NA * CHW;               // [NB, 2048]
    float* Wh1 = out + (size_t)(NA + NB) * CHW;        // [E, 2048]
    float* Wh2 = Wh1 + (size_t)NE * CHW;               // [E, 2048]

    int* cnt_a = (int*)d_ws;        // [NA] in-degree under etype2 (dst in a)
    int* cnt_b = cnt_a + NA;        // [NB] in-degree under etype1 (dst in b)

    // zero h accumulators + counts
    size_t nh4 = (size_t)(NA + NB) * CHW / 4;
    size_t nc4 = (size_t)(NA + NB) / 4;
    zero_kernel<<<2048, 256, 0, stream>>>((float4*)h_a, nh4, (int4*)d_ws, nc4);

    // in-degree histograms
    hist_kernel<<<(NE + 255) / 256, 256, 0, stream>>>(dst_e1, cnt_b, NE);
    hist_kernel<<<(NE + 255) / 256, 256, 0, stream>>>(dst_e2, cnt_a, NE);

    // etype e1: a -> b   (writes Wh1, accumulates mean into h_b)
    edge4_kernel<<<NE / EPB, 256, 0, stream>>>(feat_a, feat_b, W_e1, b_e1,
                                               src_e1, dst_e1, cnt_b, Wh1, h_b);
    // etype e2: b -> a   (writes Wh2, accumulates mean into h_a)
    edge4_kernel<<<NE / EPB, 256, 0, stream>>>(feat_b, feat_a, W_e2, b_e2,
                                               src_e2, dst_e2, cnt_a, Wh2, h_a);
}